// Round 3
// baseline (13655.302 us; speedup 1.0000x reference)
//
#include <hip/hip_runtime.h>
#include <math.h>

#define DEV static __device__ __forceinline__

DEV void load8(const float* p, float* v) {
    float4 a = *(const float4*)p;
    float4 b = *(const float4*)(p + 4);
    v[0] = a.x; v[1] = a.y; v[2] = a.z; v[3] = a.w;
    v[4] = b.x; v[5] = b.y; v[6] = b.z; v[7] = b.w;
}

// ---------- f32 GEMM: C[m,n] = sum_k A[m,k]*W[n,k] + bias[n]; N=K=512 ----------
__global__ __launch_bounds__(256) void gemm_nt512(
    const float* __restrict__ A, const float* __restrict__ W,
    const float* __restrict__ bias, float* __restrict__ C)
{
    constexpr int BK = 32, NK = 512;
    __shared__ float As[BK][64 + 4];
    __shared__ float Bs[BK][64 + 4];
    const int bm = blockIdx.y * 64, bn = blockIdx.x * 64;
    const int tid = threadIdx.x;
    const int tx = tid & 15, ty = tid >> 4;
    const int lr = tid >> 2, lk = (tid & 3) * 8;
    float acc[4][4] = {};

    for (int k0 = 0; k0 < NK; k0 += BK) {
        float va[8], vb[8];
        load8(A + (size_t)(bm + lr) * NK + k0 + lk, va);
        load8(W + (size_t)(bn + lr) * NK + k0 + lk, vb);
#pragma unroll
        for (int i = 0; i < 8; ++i) { As[lk + i][lr] = va[i]; Bs[lk + i][lr] = vb[i]; }
        __syncthreads();
#pragma unroll
        for (int kk = 0; kk < BK; ++kk) {
            float4 a4 = *(const float4*)&As[kk][ty * 4];
            float4 b4 = *(const float4*)&Bs[kk][tx * 4];
            float a[4] = {a4.x, a4.y, a4.z, a4.w};
            float b[4] = {b4.x, b4.y, b4.z, b4.w};
#pragma unroll
            for (int i = 0; i < 4; ++i)
#pragma unroll
                for (int j = 0; j < 4; ++j)
                    acc[i][j] = fmaf(a[i], b[j], acc[i][j]);
        }
        __syncthreads();
    }

    float4 bv = *(const float4*)&bias[bn + tx * 4];
    float bvv[4] = {bv.x, bv.y, bv.z, bv.w};
#pragma unroll
    for (int i = 0; i < 4; ++i) {
        size_t row = (size_t)(bm + ty * 4 + i) * NK + bn + tx * 4;
        float4 o;
        o.x = acc[i][0] + bvv[0];
        o.y = acc[i][1] + bvv[1];
        o.z = acc[i][2] + bvv[2];
        o.w = acc[i][3] + bvv[3];
        *(float4*)&C[row] = o;
    }
}

// ---------- f64-accumulate GEMM: C (f64) = A(f32) @ W(f32)^T + bias ----------
__global__ __launch_bounds__(256) void gemm_nt512_f64(
    const float* __restrict__ A, const float* __restrict__ W,
    const float* __restrict__ bias, double* __restrict__ C)
{
    constexpr int BK = 32, NK = 512;
    __shared__ float As[BK][64 + 4];
    __shared__ float Bs[BK][64 + 4];
    const int bm = blockIdx.y * 64, bn = blockIdx.x * 64;
    const int tid = threadIdx.x;
    const int tx = tid & 15, ty = tid >> 4;
    const int lr = tid >> 2, lk = (tid & 3) * 8;
    double acc[4][4] = {};

    for (int k0 = 0; k0 < NK; k0 += BK) {
        float va[8], vb[8];
        load8(A + (size_t)(bm + lr) * NK + k0 + lk, va);
        load8(W + (size_t)(bn + lr) * NK + k0 + lk, vb);
#pragma unroll
        for (int i = 0; i < 8; ++i) { As[lk + i][lr] = va[i]; Bs[lk + i][lr] = vb[i]; }
        __syncthreads();
#pragma unroll
        for (int kk = 0; kk < BK; ++kk) {
            float4 a4 = *(const float4*)&As[kk][ty * 4];
            float4 b4 = *(const float4*)&Bs[kk][tx * 4];
            double a[4] = {(double)a4.x, (double)a4.y, (double)a4.z, (double)a4.w};
            double b[4] = {(double)b4.x, (double)b4.y, (double)b4.z, (double)b4.w};
#pragma unroll
            for (int i = 0; i < 4; ++i)
#pragma unroll
                for (int j = 0; j < 4; ++j)
                    acc[i][j] = fma(a[i], b[j], acc[i][j]);
        }
        __syncthreads();
    }

    double bd[4];
#pragma unroll
    for (int j = 0; j < 4; ++j) bd[j] = (double)bias[bn + tx * 4 + j];
#pragma unroll
    for (int i = 0; i < 4; ++i) {
        size_t row = (size_t)(bm + ty * 4 + i) * NK + bn + tx * 4;
        double2 o01 = {acc[i][0] + bd[0], acc[i][1] + bd[1]};
        double2 o23 = {acc[i][2] + bd[2], acc[i][3] + bd[3]};
        *(double2*)&C[row]     = o01;
        *(double2*)&C[row + 2] = o23;
    }
}

// ---------- fused f64 scores + top-32 + softmax + f32 PV (one batch) ----------
// grid (32 qtiles, 8 heads); Kd is this batch's [4096,512] f64 projection.
__global__ __launch_bounds__(256) void topk_attn_f64(
    const double* __restrict__ Qd, const double* __restrict__ Kd,
    const float* __restrict__ Vp, float* __restrict__ Xp, int b)
{
    constexpr int LQ = 1024, LM = 4096, DK = 64, D = 512, QT = 32, MT = 32, TK = 32;
    constexpr int LDQ = DK + 1;  // 65 doubles: 2-way bank aliasing only
    __shared__ double qs[QT][LDQ];
    __shared__ double ks[MT][LDQ];
    __shared__ double sc[QT][MT + 1];
    __shared__ double topv[QT][TK + 1];
    __shared__ int    topi[QT][TK + 1];

    const int tid = threadIdx.x;
    const int qt = blockIdx.x;
    const int h  = blockIdx.y;

    // load 32x64 f64 Q tile
    {
        int r = tid >> 3, d0 = (tid & 7) * 8;
        const double* src = Qd + (size_t)(b * LQ + qt * QT + r) * D + h * DK + d0;
#pragma unroll
        for (int i = 0; i < 8; ++i) qs[r][d0 + i] = src[i];
    }
    if (tid < QT) {
#pragma unroll
        for (int t = 0; t < TK; ++t) { topv[tid][t] = -INFINITY; topi[tid][t] = 0; }
    }
    double minv = -INFINITY;
    int    minpos = 0;

    const int qg = tid >> 5;   // 0..7 -> q rows {qg, qg+8, qg+16, qg+24}
    const int mg = tid & 31;   // m col
    __syncthreads();

    for (int mc = 0; mc < LM; mc += MT) {
        // stage 32x64 f64 K tile
        {
            int r = tid >> 3, d0 = (tid & 7) * 8;
            const double* src = Kd + (size_t)(mc + r) * D + h * DK + d0;
#pragma unroll
            for (int i = 0; i < 8; ++i) ks[r][d0 + i] = src[i];
        }
        __syncthreads();

        // 32x32 scores, 4q x 1m per thread, f64 accumulate
        double a0 = 0, a1 = 0, a2 = 0, a3 = 0;
#pragma unroll
        for (int d = 0; d < DK; d += 2) {
            double kx = ks[mg][d], ky = ks[mg][d + 1];
            double q0x = qs[qg][d],      q0y = qs[qg][d + 1];
            double q1x = qs[qg + 8][d],  q1y = qs[qg + 8][d + 1];
            double q2x = qs[qg + 16][d], q2y = qs[qg + 16][d + 1];
            double q3x = qs[qg + 24][d], q3y = qs[qg + 24][d + 1];
            a0 = fma(q0x, kx, a0); a0 = fma(q0y, ky, a0);
            a1 = fma(q1x, kx, a1); a1 = fma(q1y, ky, a1);
            a2 = fma(q2x, kx, a2); a2 = fma(q2y, ky, a2);
            a3 = fma(q3x, kx, a3); a3 = fma(q3y, ky, a3);
        }
        sc[qg][mg]      = a0 * 0.125;
        sc[qg + 8][mg]  = a1 * 0.125;
        sc[qg + 16][mg] = a2 * 0.125;
        sc[qg + 24][mg] = a3 * 0.125;
        __syncthreads();

        // running top-32: one lane per q row; strict > keeps lowest index on ties
        if (tid < QT) {
            const int r = tid;
#pragma unroll 4
            for (int j = 0; j < MT; ++j) {
                double s = sc[r][j];
                if (s > minv) {
                    topv[r][minpos] = s;
                    topi[r][minpos] = mc + j;
                    double mv = topv[r][0]; int mp = 0;
#pragma unroll
                    for (int i = 1; i < TK; ++i) {
                        double v = topv[r][i];
                        if (v < mv) { mv = v; mp = i; }
                    }
                    minv = mv; minpos = mp;
                }
            }
        }
        __syncthreads();
    }

    // f64 softmax over the selected 32 (order-invariant)
    if (tid < QT) {
        const int r = tid;
        double mx = -INFINITY;
#pragma unroll
        for (int t = 0; t < TK; ++t) mx = fmax(mx, topv[r][t]);
        double e[TK], sum = 0.0;
#pragma unroll
        for (int t = 0; t < TK; ++t) { e[t] = exp(topv[r][t] - mx); sum += e[t]; }
        double inv = 1.0 / sum;
#pragma unroll
        for (int t = 0; t < TK; ++t) topv[r][t] = e[t] * inv;
    }
    __syncthreads();

    // gather V rows (f32), weighted accumulate, write X[b, q, h*64+d]
    {
        int r = tid >> 3, d0 = (tid & 7) * 8;
        float4 a0 = {0, 0, 0, 0}, a1 = {0, 0, 0, 0};
        for (int t = 0; t < TK; ++t) {
            float w = (float)topv[r][t];
            int mi  = topi[r][t];
            const float* vp = Vp + (size_t)(b * LM + mi) * D + h * DK + d0;
            float4 v0 = *(const float4*)vp;
            float4 v1 = *(const float4*)(vp + 4);
            a0.x = fmaf(w, v0.x, a0.x); a0.y = fmaf(w, v0.y, a0.y);
            a0.z = fmaf(w, v0.z, a0.z); a0.w = fmaf(w, v0.w, a0.w);
            a1.x = fmaf(w, v1.x, a1.x); a1.y = fmaf(w, v1.y, a1.y);
            a1.z = fmaf(w, v1.z, a1.z); a1.w = fmaf(w, v1.w, a1.w);
        }
        float* xp = Xp + (size_t)(b * LQ + qt * QT + r) * D + h * DK + d0;
        *(float4*)xp       = a0;
        *(float4*)(xp + 4) = a1;
    }
}

extern "C" void kernel_launch(void* const* d_in, const int* in_sizes, int n_in,
                              void* d_out, int out_size, void* d_ws, size_t ws_size,
                              hipStream_t stream) {
    const float* query = (const float*)d_in[0];
    const float* key   = (const float*)d_in[1];
    const float* value = (const float*)d_in[2];
    const float* Wq    = (const float*)d_in[3];
    const float* bq    = (const float*)d_in[4];
    const float* Wk    = (const float*)d_in[5];
    const float* bk    = (const float*)d_in[6];
    const float* Wv    = (const float*)d_in[7];
    const float* bv    = (const float*)d_in[8];
    const float* Wo    = (const float*)d_in[9];
    const float* bo    = (const float*)d_in[10];
    float* out = (float*)d_out;

    // ws layout: V f32 [32768,512] | X f32 [8192,512] | Q f64 [8192,512] | K f64 [4096,512] (per batch)
    float*  Vp = (float*)d_ws;
    float*  Xp = Vp + (size_t)32768 * 512;
    double* Qd = (double*)(Xp + (size_t)8192 * 512);
    double* Kd = Qd + (size_t)8192 * 512;

    dim3 blk(256);
    gemm_nt512_f64<<<dim3(8, 128), blk, 0, stream>>>(query, Wq, bq, Qd);
    gemm_nt512<<<dim3(8, 512), blk, 0, stream>>>(value, Wv, bv, Vp);
    for (int b = 0; b < 8; ++b) {
        gemm_nt512_f64<<<dim3(8, 64), blk, 0, stream>>>(key + (size_t)b * 4096 * 512, Wk, bk, Kd);
        topk_attn_f64<<<dim3(32, 8), blk, 0, stream>>>(Qd, Kd, Vp, Xp, b);
    }
    gemm_nt512<<<dim3(8, 128), blk, 0, stream>>>(Xp, Wo, bo, out);
}

// Round 4
// 8161.472 us; speedup vs baseline: 1.6731x; 1.6731x over previous
//
#include <hip/hip_runtime.h>
#include <math.h>

#define DEV static __device__ __forceinline__

DEV void load8(const float* p, float* v) {
    float4 a = *(const float4*)p;
    float4 b = *(const float4*)(p + 4);
    v[0] = a.x; v[1] = a.y; v[2] = a.z; v[3] = a.w;
    v[4] = b.x; v[5] = b.y; v[6] = b.z; v[7] = b.w;
}

// ---------- f32 GEMM: C[m,n] = sum_k A[m,k]*W[n,k] + bias[n]; N=K=512 ----------
__global__ __launch_bounds__(256) void gemm_nt512(
    const float* __restrict__ A, const float* __restrict__ W,
    const float* __restrict__ bias, float* __restrict__ C)
{
    constexpr int BK = 32, NK = 512;
    __shared__ float As[BK][64 + 4];
    __shared__ float Bs[BK][64 + 4];
    const int bm = blockIdx.y * 64, bn = blockIdx.x * 64;
    const int tid = threadIdx.x;
    const int tx = tid & 15, ty = tid >> 4;
    const int lr = tid >> 2, lk = (tid & 3) * 8;
    float acc[4][4] = {};

    for (int k0 = 0; k0 < NK; k0 += BK) {
        float va[8], vb[8];
        load8(A + (size_t)(bm + lr) * NK + k0 + lk, va);
        load8(W + (size_t)(bn + lr) * NK + k0 + lk, vb);
#pragma unroll
        for (int i = 0; i < 8; ++i) { As[lk + i][lr] = va[i]; Bs[lk + i][lr] = vb[i]; }
        __syncthreads();
#pragma unroll
        for (int kk = 0; kk < BK; ++kk) {
            float4 a4 = *(const float4*)&As[kk][ty * 4];
            float4 b4 = *(const float4*)&Bs[kk][tx * 4];
            float a[4] = {a4.x, a4.y, a4.z, a4.w};
            float b[4] = {b4.x, b4.y, b4.z, b4.w};
#pragma unroll
            for (int i = 0; i < 4; ++i)
#pragma unroll
                for (int j = 0; j < 4; ++j)
                    acc[i][j] = fmaf(a[i], b[j], acc[i][j]);
        }
        __syncthreads();
    }

    float4 bv = *(const float4*)&bias[bn + tx * 4];
    float bvv[4] = {bv.x, bv.y, bv.z, bv.w};
#pragma unroll
    for (int i = 0; i < 4; ++i) {
        size_t row = (size_t)(bm + ty * 4 + i) * NK + bn + tx * 4;
        float4 o;
        o.x = acc[i][0] + bvv[0];
        o.y = acc[i][1] + bvv[1];
        o.z = acc[i][2] + bvv[2];
        o.w = acc[i][3] + bvv[3];
        *(float4*)&C[row] = o;
    }
}

// ---------- f64-accumulate GEMM: C (f64) = A(f32) @ W(f32)^T + bias ----------
__global__ __launch_bounds__(256) void gemm_nt512_f64(
    const float* __restrict__ A, const float* __restrict__ W,
    const float* __restrict__ bias, double* __restrict__ C)
{
    constexpr int BK = 32, NK = 512;
    __shared__ float As[BK][64 + 4];
    __shared__ float Bs[BK][64 + 4];
    const int bm = blockIdx.y * 64, bn = blockIdx.x * 64;
    const int tid = threadIdx.x;
    const int tx = tid & 15, ty = tid >> 4;
    const int lr = tid >> 2, lk = (tid & 3) * 8;
    double acc[4][4] = {};

    for (int k0 = 0; k0 < NK; k0 += BK) {
        float va[8], vb[8];
        load8(A + (size_t)(bm + lr) * NK + k0 + lk, va);
        load8(W + (size_t)(bn + lr) * NK + k0 + lk, vb);
#pragma unroll
        for (int i = 0; i < 8; ++i) { As[lk + i][lr] = va[i]; Bs[lk + i][lr] = vb[i]; }
        __syncthreads();
#pragma unroll
        for (int kk = 0; kk < BK; ++kk) {
            float4 a4 = *(const float4*)&As[kk][ty * 4];
            float4 b4 = *(const float4*)&Bs[kk][tx * 4];
            double a[4] = {(double)a4.x, (double)a4.y, (double)a4.z, (double)a4.w};
            double b[4] = {(double)b4.x, (double)b4.y, (double)b4.z, (double)b4.w};
#pragma unroll
            for (int i = 0; i < 4; ++i)
#pragma unroll
                for (int j = 0; j < 4; ++j)
                    acc[i][j] = fma(a[i], b[j], acc[i][j]);
        }
        __syncthreads();
    }

    double bd[4];
#pragma unroll
    for (int j = 0; j < 4; ++j) bd[j] = (double)bias[bn + tx * 4 + j];
#pragma unroll
    for (int i = 0; i < 4; ++i) {
        size_t row = (size_t)(bm + ty * 4 + i) * NK + bn + tx * 4;
        double2 o01 = {acc[i][0] + bd[0], acc[i][1] + bd[1]};
        double2 o23 = {acc[i][2] + bd[2], acc[i][3] + bd[3]};
        *(double2*)&C[row]     = o01;
        *(double2*)&C[row + 2] = o23;
    }
}

// ---------- fused: f32 score screen -> top-48 -> f64 rescore -> top-32 softmax -> PV ----------
// grid (32 qtiles, 8 heads, 8 batches), 256 threads (4 waves). Wave w owns q rows 8w..8w+7.
__global__ __launch_bounds__(256) void topk_attn_fused(
    const double* __restrict__ Qd, const double* __restrict__ Kd,
    const float* __restrict__ Vp, float* __restrict__ Xp)
{
    constexpr int LQ = 1024, LM = 4096, DK = 64, D = 512, QT = 32, MT = 64, TK = 32, CAND = 48;
    __shared__ float qs[QT][68];
    __shared__ float ks[MT][68];
    __shared__ float sc[QT][65];
    __shared__ float wsel[QT][TK + 1];
    __shared__ int   isel[QT][TK + 1];

    const int tid  = threadIdx.x;
    const int lane = tid & 63;
    const int w    = tid >> 6;
    const int qt = blockIdx.x, h = blockIdx.y, b = blockIdx.z;

    // load 32x64 Q tile (f64 -> f32) for screening
    {
        int r = tid >> 3, d0 = (tid & 7) * 8;
        const double* src = Qd + ((size_t)(b * LQ + qt * QT + r) * D + h * DK + d0);
#pragma unroll
        for (int i = 0; i < 8; i += 2) {
            double2 q2 = *(const double2*)(src + i);
            qs[r][d0 + i]     = (float)q2.x;
            qs[r][d0 + i + 1] = (float)q2.y;
        }
    }

    // wave-distributed top-48 buffers: lane t (<48) holds slot t of each of 8 rows
    float bvv[8]; int bii[8];
    float curmin[8]; int minlane[8];
#pragma unroll
    for (int rr = 0; rr < 8; ++rr) {
        bvv[rr] = -INFINITY; bii[rr] = 0;
        curmin[rr] = -INFINITY; minlane[rr] = 0;
    }

    const int qg = tid >> 5;   // 0..7
    const int mg = tid & 31;
    __syncthreads();

    for (int mc = 0; mc < LM; mc += MT) {
        // stage 64x64 K tile (f64 -> f32)
        {
            int r = tid >> 2, d0 = (tid & 3) * 16;
            const double* src = Kd + ((size_t)(b * LM + mc + r) * D + h * DK + d0);
#pragma unroll
            for (int i = 0; i < 16; i += 2) {
                double2 k2 = *(const double2*)(src + i);
                ks[r][d0 + i]     = (float)k2.x;
                ks[r][d0 + i + 1] = (float)k2.y;
            }
        }
        __syncthreads();

        // 32x64 scores, 4q x 2m per thread, f32
        float acc[4][2] = {};
#pragma unroll
        for (int d = 0; d < DK; d += 4) {
            float4 qa[4], kb[2];
#pragma unroll
            for (int i = 0; i < 4; ++i) qa[i] = *(const float4*)&qs[qg + 8 * i][d];
#pragma unroll
            for (int j = 0; j < 2; ++j) kb[j] = *(const float4*)&ks[mg + 32 * j][d];
#pragma unroll
            for (int i = 0; i < 4; ++i)
#pragma unroll
                for (int j = 0; j < 2; ++j) {
                    acc[i][j] = fmaf(qa[i].x, kb[j].x, acc[i][j]);
                    acc[i][j] = fmaf(qa[i].y, kb[j].y, acc[i][j]);
                    acc[i][j] = fmaf(qa[i].z, kb[j].z, acc[i][j]);
                    acc[i][j] = fmaf(qa[i].w, kb[j].w, acc[i][j]);
                }
        }
#pragma unroll
        for (int i = 0; i < 4; ++i)
#pragma unroll
            for (int j = 0; j < 2; ++j)
                sc[qg + 8 * i][mg + 32 * j] = acc[i][j] * 0.125f;
        __syncthreads();

        // per-wave top-48 merge on rows 8w..8w+7 (ascending index => reference tie semantics)
#pragma unroll 1
        for (int rr = 0; rr < 8; ++rr) {
            const int r = 8 * w + rr;
            float s = sc[r][lane];
            unsigned long long mask = __ballot(s > curmin[rr]);
            while (mask) {
                int l = __ffsll(mask) - 1;
                mask &= mask - 1;
                float v = __shfl(s, l);
                if (v > curmin[rr]) {                    // wave-uniform
                    if (lane == minlane[rr]) { bvv[rr] = v; bii[rr] = mc + l; }
                    float mv = (lane < CAND) ? bvv[rr] : INFINITY;
                    int   ml = lane;
#pragma unroll
                    for (int k = 32; k; k >>= 1) {
                        float ov = __shfl_xor(mv, k);
                        int   ol = __shfl_xor(ml, k);
                        if (ov < mv || (ov == mv && ol < ml)) { mv = ov; ml = ol; }
                    }
                    curmin[rr] = mv; minlane[rr] = ml;   // uniform
                }
            }
        }
        __syncthreads();
    }

    // f64 rescore of 48 candidates per row; exact top-32 + softmax
#pragma unroll 1
    for (int rr = 0; rr < 8; ++rr) {
        const int r = 8 * w + rr;
        const int m = bii[rr];
        double v = -INFINITY;
        if (lane < CAND) {
            const double* qrow = Qd + ((size_t)(b * LQ + qt * QT + r) * D + h * DK);
            const double* krow = Kd + ((size_t)(b * LM + m) * D + h * DK);
            double a = 0.0;
#pragma unroll
            for (int d = 0; d < DK; d += 2) {
                double2 q2 = *(const double2*)(qrow + d);
                double2 k2 = *(const double2*)(krow + d);
                a = fma(q2.x, k2.x, a);
                a = fma(q2.y, k2.y, a);
            }
            v = a * 0.125;
        }
        // rank among the 48 candidates; tie -> lower original index
        int rank = 0;
#pragma unroll 1
        for (int s2 = 0; s2 < CAND; ++s2) {
            double vs = __shfl(v, s2);
            int    ms = __shfl(m, s2);
            if (lane < CAND && s2 != lane)
                rank += (vs > v) || (vs == v && ms < m);
        }
        // f64 softmax over rank < 32
        double mx = v;
#pragma unroll
        for (int k = 32; k; k >>= 1) mx = fmax(mx, __shfl_xor(mx, k));
        double e = (lane < CAND && rank < TK) ? exp(v - mx) : 0.0;
        double sum = e;
#pragma unroll
        for (int k = 32; k; k >>= 1) sum += __shfl_xor(sum, k);
        if (lane < CAND && rank < TK) {
            wsel[r][rank] = (float)(e / sum);
            isel[r][rank] = m;
        }
    }
    __syncthreads();

    // PV: gather selected V rows (f32), write X[b, q, h*64+d]
    {
        int r = tid >> 3, d0 = (tid & 7) * 8;
        float4 a0 = {0, 0, 0, 0}, a1 = {0, 0, 0, 0};
#pragma unroll 1
        for (int t = 0; t < TK; ++t) {
            float ww = wsel[r][t];
            int mi   = isel[r][t];
            const float* vp = Vp + ((size_t)(b * LM + mi) * D + h * DK + d0);
            float4 v0 = *(const float4*)vp;
            float4 v1 = *(const float4*)(vp + 4);
            a0.x = fmaf(ww, v0.x, a0.x); a0.y = fmaf(ww, v0.y, a0.y);
            a0.z = fmaf(ww, v0.z, a0.z); a0.w = fmaf(ww, v0.w, a0.w);
            a1.x = fmaf(ww, v1.x, a1.x); a1.y = fmaf(ww, v1.y, a1.y);
            a1.z = fmaf(ww, v1.z, a1.z); a1.w = fmaf(ww, v1.w, a1.w);
        }
        float* xp = Xp + ((size_t)(b * LQ + qt * QT + r) * D + h * DK + d0);
        *(float4*)xp       = a0;
        *(float4*)(xp + 4) = a1;
    }
}

extern "C" void kernel_launch(void* const* d_in, const int* in_sizes, int n_in,
                              void* d_out, int out_size, void* d_ws, size_t ws_size,
                              hipStream_t stream) {
    const float* query = (const float*)d_in[0];
    const float* key   = (const float*)d_in[1];
    const float* value = (const float*)d_in[2];
    const float* Wq    = (const float*)d_in[3];
    const float* bq    = (const float*)d_in[4];
    const float* Wk    = (const float*)d_in[5];
    const float* bk    = (const float*)d_in[6];
    const float* Wv    = (const float*)d_in[7];
    const float* bv    = (const float*)d_in[8];
    const float* Wo    = (const float*)d_in[9];
    const float* bo    = (const float*)d_in[10];
    float* out = (float*)d_out;

    // ws: V f32 [32768,512] | X f32 [8192,512] | Q f64 [8192,512] | K f64 [32768,512]  (~252 MB)
    float*  Vp = (float*)d_ws;
    float*  Xp = Vp + (size_t)32768 * 512;
    double* Qd = (double*)(Xp + (size_t)8192 * 512);
    double* Kd = Qd + (size_t)8192 * 512;

    dim3 blk(256);
    gemm_nt512_f64<<<dim3(8, 128), blk, 0, stream>>>(query, Wq, bq, Qd);
    gemm_nt512_f64<<<dim3(8, 512), blk, 0, stream>>>(key,   Wk, bk, Kd);
    gemm_nt512<<<dim3(8, 512), blk, 0, stream>>>(value, Wv, bv, Vp);
    topk_attn_fused<<<dim3(32, 8, 8), blk, 0, stream>>>(Qd, Kd, Vp, Xp);
    gemm_nt512<<<dim3(8, 128), blk, 0, stream>>>(Xp, Wo, bo, out);
}

// Round 5
// 3002.041 us; speedup vs baseline: 4.5487x; 2.7186x over previous
//
#include <hip/hip_runtime.h>
#include <math.h>

#define DEV static __device__ __forceinline__

DEV void load8(const float* p, float* v) {
    float4 a = *(const float4*)p;
    float4 b = *(const float4*)(p + 4);
    v[0] = a.x; v[1] = a.y; v[2] = a.z; v[3] = a.w;
    v[4] = b.x; v[5] = b.y; v[6] = b.z; v[7] = b.w;
}

// ---------- f32 GEMM: C[m,n] = sum_k A[m,k]*W[n,k] + bias[n]; N=K=512 ----------
__global__ __launch_bounds__(256) void gemm_nt512(
    const float* __restrict__ A, const float* __restrict__ W,
    const float* __restrict__ bias, float* __restrict__ C)
{
    constexpr int BK = 32, NK = 512;
    __shared__ float As[BK][64 + 4];
    __shared__ float Bs[BK][64 + 4];
    const int bm = blockIdx.y * 64, bn = blockIdx.x * 64;
    const int tid = threadIdx.x;
    const int tx = tid & 15, ty = tid >> 4;
    const int lr = tid >> 2, lk = (tid & 3) * 8;
    float acc[4][4] = {};

    for (int k0 = 0; k0 < NK; k0 += BK) {
        float va[8], vb[8];
        load8(A + (size_t)(bm + lr) * NK + k0 + lk, va);
        load8(W + (size_t)(bn + lr) * NK + k0 + lk, vb);
#pragma unroll
        for (int i = 0; i < 8; ++i) { As[lk + i][lr] = va[i]; Bs[lk + i][lr] = vb[i]; }
        __syncthreads();
#pragma unroll
        for (int kk = 0; kk < BK; ++kk) {
            float4 a4 = *(const float4*)&As[kk][ty * 4];
            float4 b4 = *(const float4*)&Bs[kk][tx * 4];
            float a[4] = {a4.x, a4.y, a4.z, a4.w};
            float b[4] = {b4.x, b4.y, b4.z, b4.w};
#pragma unroll
            for (int i = 0; i < 4; ++i)
#pragma unroll
                for (int j = 0; j < 4; ++j)
                    acc[i][j] = fmaf(a[i], b[j], acc[i][j]);
        }
        __syncthreads();
    }

    float4 bv = *(const float4*)&bias[bn + tx * 4];
    float bvv[4] = {bv.x, bv.y, bv.z, bv.w};
#pragma unroll
    for (int i = 0; i < 4; ++i) {
        size_t row = (size_t)(bm + ty * 4 + i) * NK + bn + tx * 4;
        float4 o;
        o.x = acc[i][0] + bvv[0];
        o.y = acc[i][1] + bvv[1];
        o.z = acc[i][2] + bvv[2];
        o.w = acc[i][3] + bvv[3];
        *(float4*)&C[row] = o;
    }
}

// ---------- f64-accumulate GEMM: C (f64) = A(f32) @ W(f32)^T + bias ----------
__global__ __launch_bounds__(256) void gemm_nt512_f64(
    const float* __restrict__ A, const float* __restrict__ W,
    const float* __restrict__ bias, double* __restrict__ C)
{
    constexpr int BK = 32, NK = 512;
    __shared__ float As[BK][64 + 4];
    __shared__ float Bs[BK][64 + 4];
    const int bm = blockIdx.y * 64, bn = blockIdx.x * 64;
    const int tid = threadIdx.x;
    const int tx = tid & 15, ty = tid >> 4;
    const int lr = tid >> 2, lk = (tid & 3) * 8;
    double acc[4][4] = {};

    for (int k0 = 0; k0 < NK; k0 += BK) {
        float va[8], vb[8];
        load8(A + (size_t)(bm + lr) * NK + k0 + lk, va);
        load8(W + (size_t)(bn + lr) * NK + k0 + lk, vb);
#pragma unroll
        for (int i = 0; i < 8; ++i) { As[lk + i][lr] = va[i]; Bs[lk + i][lr] = vb[i]; }
        __syncthreads();
#pragma unroll
        for (int kk = 0; kk < BK; ++kk) {
            float4 a4 = *(const float4*)&As[kk][ty * 4];
            float4 b4 = *(const float4*)&Bs[kk][tx * 4];
            double a[4] = {(double)a4.x, (double)a4.y, (double)a4.z, (double)a4.w};
            double b[4] = {(double)b4.x, (double)b4.y, (double)b4.z, (double)b4.w};
#pragma unroll
            for (int i = 0; i < 4; ++i)
#pragma unroll
                for (int j = 0; j < 4; ++j)
                    acc[i][j] = fma(a[i], b[j], acc[i][j]);
        }
        __syncthreads();
    }

    double bd[4];
#pragma unroll
    for (int j = 0; j < 4; ++j) bd[j] = (double)bias[bn + tx * 4 + j];
#pragma unroll
    for (int i = 0; i < 4; ++i) {
        size_t row = (size_t)(bm + ty * 4 + i) * NK + bn + tx * 4;
        double2 o01 = {acc[i][0] + bd[0], acc[i][1] + bd[1]};
        double2 o23 = {acc[i][2] + bd[2], acc[i][3] + bd[3]};
        *(double2*)&C[row]     = o01;
        *(double2*)&C[row + 2] = o23;
    }
}

// ---------- fused: f32 screen (per-lane reg top-24) -> f64 rescore 192 -> top-32 -> PV ----------
// grid (32 qtiles, 8 heads, 8 batches), 256 threads. Wave w, group g=lane/8 owns row 8w+g;
// lane-in-group j handles columns == j (mod 8).
__global__ __launch_bounds__(256) void topk_attn_fused(
    const double* __restrict__ Qd, const double* __restrict__ Kd,
    const float* __restrict__ Vp, float* __restrict__ Xp)
{
    constexpr int LQ = 1024, LM = 4096, DK = 64, D = 512, QT = 32, MT = 64, TK = 32, T = 24;
    // LDS: region A: ks f32[64][68] (17408 B) aliased with qd f64[32][66] (16896 B)
    //      region B: qs f32[32][68] (8704 B)  aliased with wsel f32[32][33] + isel i32[32][33]
    //      region C: sc f32[32][72] (9216 B)
    __shared__ __align__(16) char smem[17408 + 8704 + 9216];
    float  (*ks)[68]   = (float  (*)[68])(smem);
    double (*qd)[66]   = (double (*)[66])(smem);
    float  (*qs)[68]   = (float  (*)[68])(smem + 17408);
    float  (*wsel)[33] = (float  (*)[33])(smem + 17408);
    int    (*isel)[33] = (int    (*)[33])(smem + 17408 + 4224);
    float  (*sc)[72]   = (float  (*)[72])(smem + 17408 + 8704);

    const int tid  = threadIdx.x;
    const int lane = tid & 63;
    const int w    = tid >> 6;
    const int g    = lane >> 3, j = lane & 7;
    const int r    = 8 * w + g;                    // merge row owned by this lane
    const int qt = blockIdx.x, h = blockIdx.y, b = blockIdx.z;

    // stage 32x64 Q tile (f64 -> f32)
    {
        int rr = tid >> 3, d0 = (tid & 7) * 8;
        const double* src = Qd + ((size_t)(b * LQ + qt * QT + rr) * D + h * DK + d0);
#pragma unroll
        for (int i = 0; i < 8; i += 2) {
            double2 q2 = *(const double2*)(src + i);
            qs[rr][d0 + i]     = (float)q2.x;
            qs[rr][d0 + i + 1] = (float)q2.y;
        }
    }

    // per-lane top-T registers (fully unrolled access only)
    float bv[T]; int bi[T];
#pragma unroll
    for (int t = 0; t < T; ++t) { bv[t] = -INFINITY; bi[t] = 0; }
    float curmin = -INFINITY; int minpos = 0;

    const int qg = tid >> 5, mg = tid & 31;
    __syncthreads();

#pragma unroll 1
    for (int mc = 0; mc < LM; mc += MT) {
        // stage 64x64 K tile (f64 -> f32)
        {
            int rr = tid >> 2, d0 = (tid & 3) * 16;
            const double* src = Kd + ((size_t)(b * LM + mc + rr) * D + h * DK + d0);
#pragma unroll
            for (int i = 0; i < 16; i += 2) {
                double2 k2 = *(const double2*)(src + i);
                ks[rr][d0 + i]     = (float)k2.x;
                ks[rr][d0 + i + 1] = (float)k2.y;
            }
        }
        __syncthreads();

        // 32x64 scores, 4q x 2m per thread, f32
        float acc[4][2] = {};
#pragma unroll
        for (int d = 0; d < DK; d += 4) {
            float4 qa[4], kb[2];
#pragma unroll
            for (int i = 0; i < 4; ++i) qa[i] = *(const float4*)&qs[qg + 8 * i][d];
#pragma unroll
            for (int jj = 0; jj < 2; ++jj) kb[jj] = *(const float4*)&ks[mg + 32 * jj][d];
#pragma unroll
            for (int i = 0; i < 4; ++i)
#pragma unroll
                for (int jj = 0; jj < 2; ++jj) {
                    acc[i][jj] = fmaf(qa[i].x, kb[jj].x, acc[i][jj]);
                    acc[i][jj] = fmaf(qa[i].y, kb[jj].y, acc[i][jj]);
                    acc[i][jj] = fmaf(qa[i].z, kb[jj].z, acc[i][jj]);
                    acc[i][jj] = fmaf(qa[i].w, kb[jj].w, acc[i][jj]);
                }
        }
#pragma unroll
        for (int i = 0; i < 4; ++i)
#pragma unroll
            for (int jj = 0; jj < 2; ++jj)
                sc[qg + 8 * i][mg + 32 * jj] = acc[i][jj] * 0.125f;
        __syncthreads();

        // per-lane merge: 8 columns of my row, no cross-lane ops
#pragma unroll
        for (int c = 0; c < 8; ++c) {
            float v = sc[r][8 * c + j];
            if (v > curmin) {
                int idx = mc + 8 * c + j;
#pragma unroll
                for (int t = 0; t < T; ++t)
                    if (t == minpos) { bv[t] = v; bi[t] = idx; }
                float mv = bv[0]; int mp = 0;
#pragma unroll
                for (int t = 1; t < T; ++t)
                    if (bv[t] < mv) { mv = bv[t]; mp = t; }
                curmin = mv; minpos = mp;
            }
        }
        __syncthreads();
    }

    // stage q rows as f64 into LDS (overwrites ks; all ks reads are behind the last barrier)
    {
        int rr = tid >> 3, d0 = (tid & 7) * 8;
        const double* src = Qd + ((size_t)(b * LQ + qt * QT + rr) * D + h * DK + d0);
#pragma unroll
        for (int i = 0; i < 8; i += 2) {
            double2 q2 = *(const double2*)(src + i);
            qd[rr][d0 + i]     = q2.x;
            qd[rr][d0 + i + 1] = q2.y;
        }
    }
    __syncthreads();

    // f64 rescore of this lane's T candidates
    double rv[T];
#pragma unroll
    for (int t = 0; t < T; ++t) {
        const double* krow = Kd + ((size_t)(b * LM + bi[t]) * D + h * DK);
        double a = 0.0;
#pragma unroll 8
        for (int d = 0; d < DK; d += 2) {
            double2 k2 = *(const double2*)(krow + d);
            double2 q2 = *(const double2*)&qd[r][d];
            a = fma(q2.x, k2.x, a);
            a = fma(q2.y, k2.y, a);
        }
        rv[t] = a * 0.125;
    }

    // exact top-32 among the group's 192 candidates (f64 order, lower index on ties)
    unsigned cons = 0;
    double m0 = 0.0, sum_part = 0.0;
#pragma unroll 1
    for (int t32 = 0; t32 < TK; ++t32) {
        double lm = -INFINITY; int li = 0x7fffffff; int lp = -1;
#pragma unroll
        for (int t = 0; t < T; ++t) {
            bool ok = !(cons & (1u << t));
            if (ok && (rv[t] > lm || (rv[t] == lm && bi[t] < li))) {
                lm = rv[t]; li = bi[t]; lp = t;
            }
        }
        double gv = lm; int gi = li;
#pragma unroll
        for (int k = 1; k < 8; k <<= 1) {
            double ov = __shfl_xor(gv, k);
            int    oi = __shfl_xor(gi, k);
            if (ov > gv || (ov == gv && oi < gi)) { gv = ov; gi = oi; }
        }
        if (lp >= 0 && gv == lm && gi == li) cons |= 1u << lp;   // winner's owner consumes
        if (t32 == 0) m0 = gv;
        if ((t32 & 7) == j) {
            double e = exp(gv - m0);
            sum_part += e;
            isel[r][t32] = gi;
            wsel[r][t32] = (float)e;       // unnormalized; rescaled below
        }
    }
#pragma unroll
    for (int k = 1; k < 8; k <<= 1) sum_part += __shfl_xor(sum_part, k);
    {
        double inv = 1.0 / sum_part;
#pragma unroll
        for (int tt = 0; tt < 4; ++tt) {
            int t = 8 * tt + j;
            wsel[r][t] = (float)((double)wsel[r][t] * inv);
        }
    }
    __syncthreads();

    // PV: gather selected V rows (f32), write X[b, q, h*64+d]
    {
        int rr = tid >> 3, d0 = (tid & 7) * 8;
        float4 a0 = {0, 0, 0, 0}, a1 = {0, 0, 0, 0};
#pragma unroll 1
        for (int t = 0; t < TK; ++t) {
            float ww = wsel[rr][t];
            int mi   = isel[rr][t];
            const float* vp = Vp + ((size_t)(b * LM + mi) * D + h * DK + d0);
            float4 v0 = *(const float4*)vp;
            float4 v1 = *(const float4*)(vp + 4);
            a0.x = fmaf(ww, v0.x, a0.x); a0.y = fmaf(ww, v0.y, a0.y);
            a0.z = fmaf(ww, v0.z, a0.z); a0.w = fmaf(ww, v0.w, a0.w);
            a1.x = fmaf(ww, v1.x, a1.x); a1.y = fmaf(ww, v1.y, a1.y);
            a1.z = fmaf(ww, v1.z, a1.z); a1.w = fmaf(ww, v1.w, a1.w);
        }
        float* xp = Xp + ((size_t)(b * LQ + qt * QT + rr) * D + h * DK + d0);
        *(float4*)xp       = a0;
        *(float4*)(xp + 4) = a1;
    }
}

extern "C" void kernel_launch(void* const* d_in, const int* in_sizes, int n_in,
                              void* d_out, int out_size, void* d_ws, size_t ws_size,
                              hipStream_t stream) {
    const float* query = (const float*)d_in[0];
    const float* key   = (const float*)d_in[1];
    const float* value = (const float*)d_in[2];
    const float* Wq    = (const float*)d_in[3];
    const float* bq    = (const float*)d_in[4];
    const float* Wk    = (const float*)d_in[5];
    const float* bk    = (const float*)d_in[6];
    const float* Wv    = (const float*)d_in[7];
    const float* bv    = (const float*)d_in[8];
    const float* Wo    = (const float*)d_in[9];
    const float* bo    = (const float*)d_in[10];
    float* out = (float*)d_out;

    // ws: V f32 [32768,512] | X f32 [8192,512] | Q f64 [8192,512] | K f64 [32768,512]  (~252 MB)
    float*  Vp = (float*)d_ws;
    float*  Xp = Vp + (size_t)32768 * 512;
    double* Qd = (double*)(Xp + (size_t)8192 * 512);
    double* Kd = Qd + (size_t)8192 * 512;

    dim3 blk(256);
    gemm_nt512_f64<<<dim3(8, 128), blk, 0, stream>>>(query, Wq, bq, Qd);
    gemm_nt512_f64<<<dim3(8, 512), blk, 0, stream>>>(key,   Wk, bk, Kd);
    gemm_nt512<<<dim3(8, 512), blk, 0, stream>>>(value, Wv, bv, Vp);
    topk_attn_fused<<<dim3(32, 8, 8), blk, 0, stream>>>(Qd, Kd, Vp, Xp);
    gemm_nt512<<<dim3(8, 128), blk, 0, stream>>>(Xp, Wo, bo, out);
}